// Round 4
// baseline (5460.947 us; speedup 1.0000x reference)
//
#include <hip/hip_runtime.h>
#include <hip/hip_bf16.h>

// Problem constants
#define TTOK   4096          // B*S tokens
#define DD     512           // model dim D
#define DO     1024          // projected dim O
#define NHEAD  8
#define HSZ    64
#define NEXP   8
#define FFD    4096          // expert hidden
#define SEQ    256
#define NBATCH 16
#define MAXROWS 9216         // 8192 assignments + 8*128 pad
#define BM 128
#define BN 128
#define BK 16
#define MAXTILES (MAXROWS/BM)   // 72

// ---------------- helpers ----------------
__device__ inline float block_reduce_sum(float v, float* smem) {
  #pragma unroll
  for (int off = 32; off; off >>= 1) v += __shfl_xor(v, off);
  int wid = threadIdx.x >> 6;
  __syncthreads();
  if ((threadIdx.x & 63) == 0) smem[wid] = v;
  __syncthreads();
  return smem[0] + smem[1] + smem[2] + smem[3];
}

// ---------------- elementwise / LN ----------------
__global__ __launch_bounds__(256) void zero_kernel(float* p, int n) {
  int i = blockIdx.x * 256 + threadIdx.x;
  if (i < n) p[i] = 0.f;
}

__global__ __launch_bounds__(256) void embed_kernel(
    const int* __restrict__ ids, const float* __restrict__ emb,
    const float* __restrict__ pe, float* __restrict__ x) {
  int t = blockIdx.x;
  int s = t & (SEQ - 1);
  int id = ids[t];
  const float* er = emb + (size_t)id * DD;
  const float* pr = pe + (size_t)s * DD;
  float* xr = x + (size_t)t * DD;
  for (int c = threadIdx.x; c < DD; c += 256) xr[c] = er[c] + pr[c];
}

template <int DIM>
__global__ __launch_bounds__(256) void ln_kernel(
    const float* __restrict__ in, const float* __restrict__ g,
    const float* __restrict__ b, float* __restrict__ out) {
  __shared__ float red[4];
  constexpr int PER = DIM / 256;
  int t = blockIdx.x;
  const float* row = in + (size_t)t * DIM;
  float v[PER];
  float s = 0.f;
  #pragma unroll
  for (int i = 0; i < PER; i++) { v[i] = row[threadIdx.x + i * 256]; s += v[i]; }
  s = block_reduce_sum(s, red);
  float mean = s * (1.0f / DIM);
  float sq = 0.f;
  #pragma unroll
  for (int i = 0; i < PER; i++) { float d = v[i] - mean; sq += d * d; }
  sq = block_reduce_sum(sq, red);
  float inv = rsqrtf(sq * (1.0f / DIM) + 1e-5f);
  float* orow = out + (size_t)t * DIM;
  #pragma unroll
  for (int i = 0; i < PER; i++) {
    int c = threadIdx.x + i * 256;
    orow[c] = (v[i] - mean) * inv * g[c] + b[c];
  }
}

// ---------------- generic fp32 GEMM: C = A@B (+bias)(+resid)(relu) ----------------
// A [M,K] row-major, B [K,N] row-major, all dims multiples of tile.
__global__ __launch_bounds__(256) void gemm_f32(
    const float* __restrict__ A, const float* __restrict__ B,
    float* __restrict__ C, int M, int N, int Kd,
    const float* __restrict__ bias, const float* __restrict__ resid, int relu) {
  __shared__ float As[BK][BM + 4];
  __shared__ float Bs[BK][BN + 4];
  int tid = threadIdx.x;
  int row0 = blockIdx.y * BM, col0 = blockIdx.x * BN;
  int tx = tid & 15, ty = tid >> 4;
  int arow = tid >> 1, acol = (tid & 1) * 8;
  int brow = tid >> 4, bcol = (tid & 15) * 8;
  const float* Aptr = A + (size_t)(row0 + arow) * Kd;
  float acc[8][8] = {};
  for (int k0 = 0; k0 < Kd; k0 += BK) {
    float4 a0 = *(const float4*)(Aptr + k0 + acol);
    float4 a1 = *(const float4*)(Aptr + k0 + acol + 4);
    As[acol + 0][arow] = a0.x; As[acol + 1][arow] = a0.y;
    As[acol + 2][arow] = a0.z; As[acol + 3][arow] = a0.w;
    As[acol + 4][arow] = a1.x; As[acol + 5][arow] = a1.y;
    As[acol + 6][arow] = a1.z; As[acol + 7][arow] = a1.w;
    const float* Bp = B + (size_t)(k0 + brow) * N + col0 + bcol;
    *(float4*)&Bs[brow][bcol]     = *(const float4*)(Bp);
    *(float4*)&Bs[brow][bcol + 4] = *(const float4*)(Bp + 4);
    __syncthreads();
    #pragma unroll
    for (int kk = 0; kk < BK; kk++) {
      float4 av0 = *(const float4*)&As[kk][ty * 8];
      float4 av1 = *(const float4*)&As[kk][ty * 8 + 4];
      float4 bv0 = *(const float4*)&Bs[kk][tx * 8];
      float4 bv1 = *(const float4*)&Bs[kk][tx * 8 + 4];
      float a_[8] = {av0.x, av0.y, av0.z, av0.w, av1.x, av1.y, av1.z, av1.w};
      float b_[8] = {bv0.x, bv0.y, bv0.z, bv0.w, bv1.x, bv1.y, bv1.z, bv1.w};
      #pragma unroll
      for (int i = 0; i < 8; i++)
        #pragma unroll
        for (int j = 0; j < 8; j++) acc[i][j] = fmaf(a_[i], b_[j], acc[i][j]);
    }
    __syncthreads();
  }
  #pragma unroll
  for (int i = 0; i < 8; i++) {
    int r = row0 + ty * 8 + i;
    float* crow = C + (size_t)r * N;
    #pragma unroll
    for (int j = 0; j < 8; j++) {
      int c = col0 + tx * 8 + j;
      float vv = acc[i][j];
      if (bias) vv += bias[c];
      if (resid) vv += resid[(size_t)r * N + c];
      if (relu) vv = fmaxf(vv, 0.f);
      crow[c] = vv;
    }
  }
}

// ---------------- attention (causal MHA, online softmax) ----------------
// one wave per (b, h, 64-query chunk)
__global__ __launch_bounds__(64) void attn_kernel(
    const float* __restrict__ q, const float* __restrict__ k,
    const float* __restrict__ v, float* __restrict__ out) {
  __shared__ float Qs[64][68];
  __shared__ float Ks[64][64];
  __shared__ float Vs[64][64];
  int l = threadIdx.x;
  int qc = blockIdx.x & 3;
  int h = (blockIdx.x >> 2) & 7;
  int b = blockIdx.x >> 5;
  size_t base = ((size_t)b * SEQ) * DD + h * HSZ;
  // stage Q (scaled by 1/sqrt(HS)=1/8)
  for (int rr = 0; rr < 64; rr++)
    Qs[rr][l] = q[base + (size_t)(qc * 64 + rr) * DD + l] * 0.125f;
  __syncthreads();
  float qreg[64];
  #pragma unroll
  for (int d4 = 0; d4 < 16; d4++) {
    float4 t = *(const float4*)&Qs[l][d4 * 4];
    qreg[d4 * 4 + 0] = t.x; qreg[d4 * 4 + 1] = t.y;
    qreg[d4 * 4 + 2] = t.z; qreg[d4 * 4 + 3] = t.w;
  }
  float acc[64];
  #pragma unroll
  for (int d = 0; d < 64; d++) acc[d] = 0.f;
  float m = -INFINITY, lsum = 0.f;
  int qrow = qc * 64 + l;
  #pragma unroll 1
  for (int kc = 0; kc <= qc; kc++) {
    __syncthreads();
    for (int rr = 0; rr < 64; rr++) {
      Ks[rr][l] = k[base + (size_t)(kc * 64 + rr) * DD + l];
      Vs[rr][l] = v[base + (size_t)(kc * 64 + rr) * DD + l];
    }
    __syncthreads();
    #pragma unroll 1
    for (int sub = 0; sub < 4; sub++) {
      int j0 = sub * 16;
      float s[16];
      #pragma unroll
      for (int jj = 0; jj < 16; jj++) {
        float a = 0.f;
        #pragma unroll
        for (int d4 = 0; d4 < 16; d4++) {
          float4 kv = *(const float4*)&Ks[j0 + jj][d4 * 4];
          a = fmaf(qreg[d4 * 4 + 0], kv.x, a);
          a = fmaf(qreg[d4 * 4 + 1], kv.y, a);
          a = fmaf(qreg[d4 * 4 + 2], kv.z, a);
          a = fmaf(qreg[d4 * 4 + 3], kv.w, a);
        }
        int kglob = kc * 64 + j0 + jj;
        s[jj] = (kglob <= qrow) ? a : -INFINITY;
      }
      float cm = m;
      #pragma unroll
      for (int jj = 0; jj < 16; jj++) cm = fmaxf(cm, s[jj]);
      if (cm == -INFINITY) continue;  // fully masked sub-chunk
      float scale = __expf(m - cm);   // m==-inf -> 0
      lsum *= scale;
      #pragma unroll
      for (int jj = 0; jj < 16; jj++) { s[jj] = __expf(s[jj] - cm); lsum += s[jj]; }
      #pragma unroll
      for (int d = 0; d < 64; d++) acc[d] *= scale;
      #pragma unroll
      for (int jj = 0; jj < 16; jj++) {
        #pragma unroll
        for (int d4 = 0; d4 < 16; d4++) {
          float4 vv = *(const float4*)&Vs[j0 + jj][d4 * 4];
          acc[d4 * 4 + 0] = fmaf(s[jj], vv.x, acc[d4 * 4 + 0]);
          acc[d4 * 4 + 1] = fmaf(s[jj], vv.y, acc[d4 * 4 + 1]);
          acc[d4 * 4 + 2] = fmaf(s[jj], vv.z, acc[d4 * 4 + 2]);
          acc[d4 * 4 + 3] = fmaf(s[jj], vv.w, acc[d4 * 4 + 3]);
        }
      }
      m = cm;
    }
  }
  float inv = 1.f / lsum;
  float* orow = out + base + (size_t)qrow * DD;
  #pragma unroll
  for (int d = 0; d < 64; d++) orow[d] = acc[d] * inv;
}

// ---------------- MoE router ----------------
__global__ __launch_bounds__(64) void router_kernel(
    const float* __restrict__ Y, const float* __restrict__ RW,
    const float* __restrict__ RB, const float* __restrict__ NW,
    const float* __restrict__ NBv, const float* __restrict__ noise,
    int* __restrict__ idx, float* __restrict__ gate, int* __restrict__ counts) {
  int t = blockIdx.x;
  int l = threadIdx.x;
  float accr[8] = {}, accn[8] = {};
  for (int i = l; i < DO; i += 64) {
    float yv = Y[(size_t)t * DO + i];
    float4 r0 = *(const float4*)(RW + (size_t)i * 8);
    float4 r1 = *(const float4*)(RW + (size_t)i * 8 + 4);
    float4 n0 = *(const float4*)(NW + (size_t)i * 8);
    float4 n1 = *(const float4*)(NW + (size_t)i * 8 + 4);
    accr[0] = fmaf(yv, r0.x, accr[0]); accr[1] = fmaf(yv, r0.y, accr[1]);
    accr[2] = fmaf(yv, r0.z, accr[2]); accr[3] = fmaf(yv, r0.w, accr[3]);
    accr[4] = fmaf(yv, r1.x, accr[4]); accr[5] = fmaf(yv, r1.y, accr[5]);
    accr[6] = fmaf(yv, r1.z, accr[6]); accr[7] = fmaf(yv, r1.w, accr[7]);
    accn[0] = fmaf(yv, n0.x, accn[0]); accn[1] = fmaf(yv, n0.y, accn[1]);
    accn[2] = fmaf(yv, n0.z, accn[2]); accn[3] = fmaf(yv, n0.w, accn[3]);
    accn[4] = fmaf(yv, n1.x, accn[4]); accn[5] = fmaf(yv, n1.y, accn[5]);
    accn[6] = fmaf(yv, n1.z, accn[6]); accn[7] = fmaf(yv, n1.w, accn[7]);
  }
  #pragma unroll
  for (int e = 0; e < 8; e++) {
    #pragma unroll
    for (int off = 32; off; off >>= 1) {
      accr[e] += __shfl_xor(accr[e], off);
      accn[e] += __shfl_xor(accn[e], off);
    }
  }
  if (l == 0) {
    float noisy[8];
    #pragma unroll
    for (int e = 0; e < 8; e++) {
      float nl = accn[e] + NBv[e];
      float sp = nl > 0.f ? nl + log1pf(expf(-nl)) : log1pf(expf(nl));
      noisy[e] = accr[e] + RB[e] + noise[(size_t)t * 8 + e] * sp;
    }
    int i0 = 0;
    #pragma unroll
    for (int e = 1; e < 8; e++) if (noisy[e] > noisy[i0]) i0 = e;
    int i1 = -1;
    #pragma unroll
    for (int e = 0; e < 8; e++)
      if (e != i0 && (i1 < 0 || noisy[e] > noisy[i1])) i1 = e;
    float v0 = noisy[i0], v1 = noisy[i1];
    float e1 = expf(v1 - v0);
    float inv = 1.f / (1.f + e1);
    idx[2 * t] = i0; idx[2 * t + 1] = i1;
    gate[2 * t] = inv; gate[2 * t + 1] = e1 * inv;
    atomicAdd(&counts[i0], 1);
    atomicAdd(&counts[i1], 1);
  }
}

__global__ void init_kernel(int* assign_tok, int* counts) {
  int i = blockIdx.x * 256 + threadIdx.x;
  if (i < MAXROWS) assign_tok[i] = -1;
  if (i < NEXP) counts[i] = 0;
}

__global__ void prefix_kernel(const int* counts, int* offs, int* cursor) {
  if (threadIdx.x == 0 && blockIdx.x == 0) {
    int o = 0;
    offs[0] = 0;
    for (int e = 0; e < NEXP; e++) {
      cursor[e] = 0;
      o += ((counts[e] + BM - 1) / BM) * BM;
      offs[e + 1] = o;
    }
  }
}

__global__ __launch_bounds__(256) void build_kernel(
    const int* __restrict__ idx, const float* __restrict__ gate,
    const int* __restrict__ offs, int* cursor,
    int* assign_tok, float* assign_gate) {
  int t = blockIdx.x * 256 + threadIdx.x;
  if (t >= TTOK) return;
  for (int k = 0; k < 2; k++) {
    int e = idx[2 * t + k];
    int pos = atomicAdd(&cursor[e], 1);
    int r = offs[e] + pos;
    assign_tok[r] = t;
    assign_gate[r] = gate[2 * t + k];
  }
}

// ---------------- grouped expert GEMMs ----------------
// H[row] = relu(Y[tok(row)] @ W1[e] + b1[e]);  rows grouped per expert, 128-aligned
__global__ __launch_bounds__(256) void moe_gemm1(
    const float* __restrict__ Y, const float* __restrict__ W1,
    const float* __restrict__ B1, const int* __restrict__ offs,
    const int* __restrict__ assign_tok, float* __restrict__ Hbuf) {
  __shared__ float As[BK][BM + 4];
  __shared__ float Bs[BK][BN + 4];
  int row0 = blockIdx.y * BM;
  if (row0 >= offs[NEXP]) return;
  int e = 0;
  while (offs[e + 1] <= row0) e++;
  int tid = threadIdx.x;
  int col0 = blockIdx.x * BN;
  int tx = tid & 15, ty = tid >> 4;
  int arow = tid >> 1, acol = (tid & 1) * 8;
  int brow = tid >> 4, bcol = (tid & 15) * 8;
  int tok = assign_tok[row0 + arow];
  const float* Aptr = Y + (size_t)(tok < 0 ? 0 : tok) * DO;
  const float* Bbase = W1 + (size_t)e * DO * FFD;
  float acc[8][8] = {};
  for (int k0 = 0; k0 < DO; k0 += BK) {
    float4 a0 = *(const float4*)(Aptr + k0 + acol);
    float4 a1 = *(const float4*)(Aptr + k0 + acol + 4);
    As[acol + 0][arow] = a0.x; As[acol + 1][arow] = a0.y;
    As[acol + 2][arow] = a0.z; As[acol + 3][arow] = a0.w;
    As[acol + 4][arow] = a1.x; As[acol + 5][arow] = a1.y;
    As[acol + 6][arow] = a1.z; As[acol + 7][arow] = a1.w;
    const float* Bp = Bbase + (size_t)(k0 + brow) * FFD + col0 + bcol;
    *(float4*)&Bs[brow][bcol]     = *(const float4*)(Bp);
    *(float4*)&Bs[brow][bcol + 4] = *(const float4*)(Bp + 4);
    __syncthreads();
    #pragma unroll
    for (int kk = 0; kk < BK; kk++) {
      float4 av0 = *(const float4*)&As[kk][ty * 8];
      float4 av1 = *(const float4*)&As[kk][ty * 8 + 4];
      float4 bv0 = *(const float4*)&Bs[kk][tx * 8];
      float4 bv1 = *(const float4*)&Bs[kk][tx * 8 + 4];
      float a_[8] = {av0.x, av0.y, av0.z, av0.w, av1.x, av1.y, av1.z, av1.w};
      float b_[8] = {bv0.x, bv0.y, bv0.z, bv0.w, bv1.x, bv1.y, bv1.z, bv1.w};
      #pragma unroll
      for (int i = 0; i < 8; i++)
        #pragma unroll
        for (int j = 0; j < 8; j++) acc[i][j] = fmaf(a_[i], b_[j], acc[i][j]);
    }
    __syncthreads();
  }
  #pragma unroll
  for (int i = 0; i < 8; i++) {
    int r = row0 + ty * 8 + i;
    float* hrow = Hbuf + (size_t)r * FFD;
    #pragma unroll
    for (int j = 0; j < 8; j++) {
      int c = col0 + tx * 8 + j;
      hrow[c] = fmaxf(acc[i][j] + B1[(size_t)e * FFD + c], 0.f);
    }
  }
}

// Out[tok(row)] += gate(row) * (H[row] @ W2[e] + b2[e])
__global__ __launch_bounds__(256) void moe_gemm2(
    const float* __restrict__ Hbuf, const float* __restrict__ W2,
    const float* __restrict__ B2, const int* __restrict__ offs,
    const int* __restrict__ assign_tok, const float* __restrict__ assign_gate,
    float* __restrict__ Out) {
  __shared__ float As[BK][BM + 4];
  __shared__ float Bs[BK][BN + 4];
  int row0 = blockIdx.y * BM;
  if (row0 >= offs[NEXP]) return;
  int e = 0;
  while (offs[e + 1] <= row0) e++;
  int tid = threadIdx.x;
  int col0 = blockIdx.x * BN;
  int tx = tid & 15, ty = tid >> 4;
  int arow = tid >> 1, acol = (tid & 1) * 8;
  int brow = tid >> 4, bcol = (tid & 15) * 8;
  const float* Aptr = Hbuf + (size_t)(row0 + arow) * FFD;
  const float* Bbase = W2 + (size_t)e * FFD * DO;
  float acc[8][8] = {};
  for (int k0 = 0; k0 < FFD; k0 += BK) {
    float4 a0 = *(const float4*)(Aptr + k0 + acol);
    float4 a1 = *(const float4*)(Aptr + k0 + acol + 4);
    As[acol + 0][arow] = a0.x; As[acol + 1][arow] = a0.y;
    As[acol + 2][arow] = a0.z; As[acol + 3][arow] = a0.w;
    As[acol + 4][arow] = a1.x; As[acol + 5][arow] = a1.y;
    As[acol + 6][arow] = a1.z; As[acol + 7][arow] = a1.w;
    const float* Bp = Bbase + (size_t)(k0 + brow) * DO + col0 + bcol;
    *(float4*)&Bs[brow][bcol]     = *(const float4*)(Bp);
    *(float4*)&Bs[brow][bcol + 4] = *(const float4*)(Bp + 4);
    __syncthreads();
    #pragma unroll
    for (int kk = 0; kk < BK; kk++) {
      float4 av0 = *(const float4*)&As[kk][ty * 8];
      float4 av1 = *(const float4*)&As[kk][ty * 8 + 4];
      float4 bv0 = *(const float4*)&Bs[kk][tx * 8];
      float4 bv1 = *(const float4*)&Bs[kk][tx * 8 + 4];
      float a_[8] = {av0.x, av0.y, av0.z, av0.w, av1.x, av1.y, av1.z, av1.w};
      float b_[8] = {bv0.x, bv0.y, bv0.z, bv0.w, bv1.x, bv1.y, bv1.z, bv1.w};
      #pragma unroll
      for (int i = 0; i < 8; i++)
        #pragma unroll
        for (int j = 0; j < 8; j++) acc[i][j] = fmaf(a_[i], b_[j], acc[i][j]);
    }
    __syncthreads();
  }
  #pragma unroll
  for (int i = 0; i < 8; i++) {
    int r = row0 + ty * 8 + i;
    int tok = assign_tok[r];
    if (tok < 0) continue;
    float g = assign_gate[r];
    #pragma unroll
    for (int j = 0; j < 8; j++) {
      int c = col0 + tx * 8 + j;
      atomicAdd(&Out[(size_t)tok * DO + c], g * (acc[i][j] + B2[(size_t)e * DO + c]));
    }
  }
}

// ---------------- epilogue ----------------
__global__ __launch_bounds__(256) void mean_kernel(const float* __restrict__ second,
                                                   float* __restrict__ tv) {
  int o = blockIdx.x * 256 + threadIdx.x;
  int b = blockIdx.y;
  float s = 0.f;
  for (int ss = 0; ss < SEQ; ss++) s += second[((size_t)b * SEQ + ss) * DO + o];
  tv[(size_t)b * DO + o] = s * (1.f / SEQ);
}

__global__ __launch_bounds__(256) void cls_kernel(const float* __restrict__ tv,
                                                  const float* __restrict__ cw,
                                                  const float* __restrict__ cb,
                                                  float* __restrict__ outc) {
  __shared__ float red[4];
  int b = blockIdx.x;
  float s = 0.f;
  for (int o = threadIdx.x; o < DO; o += 256) s += tv[(size_t)b * DO + o] * cw[o];
  s = block_reduce_sum(s, red);
  if (threadIdx.x == 0) outc[b] = s + cb[0];
}

// ---------------- launch ----------------
extern "C" void kernel_launch(void* const* d_in, const int* in_sizes, int n_in,
                              void* d_out, int out_size, void* d_ws, size_t ws_size,
                              hipStream_t stream) {
  const int*   ids   = (const int*)d_in[0];
  const float* emb   = (const float*)d_in[2];
  const float* pe    = (const float*)d_in[3];
  const float* wq    = (const float*)d_in[4];
  const float* wk    = (const float*)d_in[5];
  const float* wv    = (const float*)d_in[6];
  const float* wo    = (const float*)d_in[7];
  const float* bo    = (const float*)d_in[8];
  const float* ln1g  = (const float*)d_in[9];
  const float* ln1b  = (const float*)d_in[10];
  const float* projw = (const float*)d_in[11];
  const float* projb = (const float*)d_in[12];
  const float* ln2g  = (const float*)d_in[13];
  const float* ln2b  = (const float*)d_in[14];
  const float* ln3g  = (const float*)d_in[15];
  const float* ln3b  = (const float*)d_in[16];
  const float* clsw  = (const float*)d_in[17];
  const float* clsb  = (const float*)d_in[18];
  const float* rwp[2]  = {(const float*)d_in[19], (const float*)d_in[28]};
  const float* rbp[2]  = {(const float*)d_in[20], (const float*)d_in[29]};
  const float* nwp[2]  = {(const float*)d_in[21], (const float*)d_in[30]};
  const float* nbp[2]  = {(const float*)d_in[22], (const float*)d_in[31]};
  const float* ew1[2]  = {(const float*)d_in[23], (const float*)d_in[32]};
  const float* eb1[2]  = {(const float*)d_in[24], (const float*)d_in[33]};
  const float* ew2[2]  = {(const float*)d_in[25], (const float*)d_in[34]};
  const float* eb2[2]  = {(const float*)d_in[26], (const float*)d_in[35]};
  const float* noz[2]  = {(const float*)d_in[27], (const float*)d_in[36]};

  char* w = (char*)d_ws;
  auto alloc = [&](size_t bytes) {
    char* p = w;
    w += (bytes + 255) & ~(size_t)255;
    return p;
  };
  float* x     = (float*)alloc((size_t)TTOK * DD * 4);
  float* xln   = (float*)alloc((size_t)TTOK * DD * 4);
  float* qb    = (float*)alloc((size_t)TTOK * DD * 4);
  float* kb    = (float*)alloc((size_t)TTOK * DD * 4);
  float* vb    = (float*)alloc((size_t)TTOK * DD * 4);
  float* attnb = (float*)alloc((size_t)TTOK * DD * 4);
  float* x2    = (float*)alloc((size_t)TTOK * DD * 4);
  float* x3    = (float*)alloc((size_t)TTOK * DO * 4);
  float* y     = (float*)alloc((size_t)TTOK * DO * 4);
  float* Hbuf  = (float*)alloc((size_t)MAXROWS * FFD * 4);
  int*   idxb  = (int*)alloc((size_t)TTOK * 2 * 4);
  float* gateb = (float*)alloc((size_t)TTOK * 2 * 4);
  int* counts  = (int*)alloc(256);
  int* offs    = (int*)alloc(256);
  int* cursor  = (int*)alloc(256);
  int* assign_tok    = (int*)alloc((size_t)MAXROWS * 4);
  float* assign_gate = (float*)alloc((size_t)MAXROWS * 4);

  float* out_first  = (float*)d_out;
  float* out_second = out_first + (size_t)TTOK * DO;
  float* tv         = out_second + (size_t)TTOK * DO;
  float* outc       = tv + (size_t)NBATCH * DO;

  zero_kernel<<<(out_size + 255) / 256, 256, 0, stream>>>((float*)d_out, out_size);
  embed_kernel<<<TTOK, 256, 0, stream>>>(ids, emb, pe, x);
  ln_kernel<DD><<<TTOK, 256, 0, stream>>>(x, ln1g, ln1b, xln);
  gemm_f32<<<dim3(DD / BN, TTOK / BM), 256, 0, stream>>>(xln, wq, qb, TTOK, DD, DD, nullptr, nullptr, 0);
  gemm_f32<<<dim3(DD / BN, TTOK / BM), 256, 0, stream>>>(xln, wk, kb, TTOK, DD, DD, nullptr, nullptr, 0);
  gemm_f32<<<dim3(DD / BN, TTOK / BM), 256, 0, stream>>>(xln, wv, vb, TTOK, DD, DD, nullptr, nullptr, 0);
  attn_kernel<<<NBATCH * NHEAD * (SEQ / 64), 64, 0, stream>>>(qb, kb, vb, attnb);
  gemm_f32<<<dim3(DD / BN, TTOK / BM), 256, 0, stream>>>(attnb, wo, x2, TTOK, DD, DD, bo, x, 0);
  gemm_f32<<<dim3(DO / BN, TTOK / BM), 256, 0, stream>>>(x2, projw, x3, TTOK, DO, DD, projb, nullptr, 0);

  for (int p = 0; p < 2; p++) {
    const float* lng = p ? ln3g : ln2g;
    const float* lnb = p ? ln3b : ln2b;
    float* outp = p ? out_second : out_first;
    ln_kernel<DO><<<TTOK, 256, 0, stream>>>(x3, lng, lnb, y);
    init_kernel<<<(MAXROWS + 255) / 256, 256, 0, stream>>>(assign_tok, counts);
    router_kernel<<<TTOK, 64, 0, stream>>>(y, rwp[p], rbp[p], nwp[p], nbp[p], noz[p],
                                           idxb, gateb, counts);
    prefix_kernel<<<1, 64, 0, stream>>>(counts, offs, cursor);
    build_kernel<<<(TTOK + 255) / 256, 256, 0, stream>>>(idxb, gateb, offs, cursor,
                                                         assign_tok, assign_gate);
    moe_gemm1<<<dim3(FFD / BN, MAXTILES), 256, 0, stream>>>(y, ew1[p], eb1[p], offs,
                                                            assign_tok, Hbuf);
    moe_gemm2<<<dim3(DO / BN, MAXTILES), 256, 0, stream>>>(Hbuf, ew2[p], eb2[p], offs,
                                                           assign_tok, assign_gate, outp);
  }
  mean_kernel<<<dim3(DO / 256, NBATCH), 256, 0, stream>>>(out_second, tv);
  cls_kernel<<<NBATCH, 256, 0, stream>>>(tv, clsw, clsb, outc);
}

// Round 6
// 2130.696 us; speedup vs baseline: 2.5630x; 2.5630x over previous
//
#include <hip/hip_runtime.h>
#include <hip/hip_bf16.h>

// Problem constants
#define TTOK   4096          // B*S tokens
#define DD     512           // model dim D
#define DO     1024          // projected dim O
#define NHEAD  8
#define HSZ    64
#define NEXP   8
#define FFD    4096          // expert hidden
#define SEQ    256
#define NBATCH 16
#define MAXROWS 9216         // 8192 assignments + 8*128 pad
#define BM 128
#define BN 128
#define BK 16
#define MAXTILES (MAXROWS/BM)   // 72

typedef __attribute__((ext_vector_type(8))) short short8v;
typedef __attribute__((ext_vector_type(4))) float f32x4;

__device__ inline short f2bf(float f) {
  union { float f; unsigned u; } x; x.f = f;
  unsigned r = (x.u + 0x7FFFu + ((x.u >> 16) & 1u)) >> 16;
  return (short)r;
}

// ---------------- helpers ----------------
__device__ inline float block_reduce_sum(float v, float* smem) {
  #pragma unroll
  for (int off = 32; off; off >>= 1) v += __shfl_xor(v, off);
  int wid = threadIdx.x >> 6;
  __syncthreads();
  if ((threadIdx.x & 63) == 0) smem[wid] = v;
  __syncthreads();
  return smem[0] + smem[1] + smem[2] + smem[3];
}

// ---------------- elementwise / LN ----------------
__global__ __launch_bounds__(256) void zero_kernel(float* p, int n) {
  int i = blockIdx.x * 256 + threadIdx.x;
  if (i < n) p[i] = 0.f;
}

__global__ __launch_bounds__(256) void embed_kernel(
    const int* __restrict__ ids, const float* __restrict__ emb,
    const float* __restrict__ pe, float* __restrict__ x) {
  int t = blockIdx.x;
  int s = t & (SEQ - 1);
  int id = ids[t];
  const float* er = emb + (size_t)id * DD;
  const float* pr = pe + (size_t)s * DD;
  float* xr = x + (size_t)t * DD;
  for (int c = threadIdx.x; c < DD; c += 256) xr[c] = er[c] + pr[c];
}

template <int DIM>
__global__ __launch_bounds__(256) void ln_kernel(
    const float* __restrict__ in, const float* __restrict__ g,
    const float* __restrict__ b, float* __restrict__ out) {
  __shared__ float red[4];
  constexpr int PER = DIM / 256;
  int t = blockIdx.x;
  const float* row = in + (size_t)t * DIM;
  float v[PER];
  float s = 0.f;
  #pragma unroll
  for (int i = 0; i < PER; i++) { v[i] = row[threadIdx.x + i * 256]; s += v[i]; }
  s = block_reduce_sum(s, red);
  float mean = s * (1.0f / DIM);
  float sq = 0.f;
  #pragma unroll
  for (int i = 0; i < PER; i++) { float d = v[i] - mean; sq += d * d; }
  sq = block_reduce_sum(sq, red);
  float inv = rsqrtf(sq * (1.0f / DIM) + 1e-5f);
  float* orow = out + (size_t)t * DIM;
  #pragma unroll
  for (int i = 0; i < PER; i++) {
    int c = threadIdx.x + i * 256;
    orow[c] = (v[i] - mean) * inv * g[c] + b[c];
  }
}

// ---------------- generic fp32 GEMM (dense path; feeds router, kept fp32) ------
__global__ __launch_bounds__(256) void gemm_f32(
    const float* __restrict__ A, const float* __restrict__ B,
    float* __restrict__ C, int M, int N, int Kd,
    const float* __restrict__ bias, const float* __restrict__ resid, int relu) {
  __shared__ float As[BK][BM + 4];
  __shared__ float Bs[BK][BN + 4];
  int tid = threadIdx.x;
  int row0 = blockIdx.y * BM, col0 = blockIdx.x * BN;
  int tx = tid & 15, ty = tid >> 4;
  int arow = tid >> 1, acol = (tid & 1) * 8;
  int brow = tid >> 4, bcol = (tid & 15) * 8;
  const float* Aptr = A + (size_t)(row0 + arow) * Kd;
  float acc[8][8] = {};
  for (int k0 = 0; k0 < Kd; k0 += BK) {
    float4 a0 = *(const float4*)(Aptr + k0 + acol);
    float4 a1 = *(const float4*)(Aptr + k0 + acol + 4);
    As[acol + 0][arow] = a0.x; As[acol + 1][arow] = a0.y;
    As[acol + 2][arow] = a0.z; As[acol + 3][arow] = a0.w;
    As[acol + 4][arow] = a1.x; As[acol + 5][arow] = a1.y;
    As[acol + 6][arow] = a1.z; As[acol + 7][arow] = a1.w;
    const float* Bp = B + (size_t)(k0 + brow) * N + col0 + bcol;
    *(float4*)&Bs[brow][bcol]     = *(const float4*)(Bp);
    *(float4*)&Bs[brow][bcol + 4] = *(const float4*)(Bp + 4);
    __syncthreads();
    #pragma unroll
    for (int kk = 0; kk < BK; kk++) {
      float4 av0 = *(const float4*)&As[kk][ty * 8];
      float4 av1 = *(const float4*)&As[kk][ty * 8 + 4];
      float4 bv0 = *(const float4*)&Bs[kk][tx * 8];
      float4 bv1 = *(const float4*)&Bs[kk][tx * 8 + 4];
      float a_[8] = {av0.x, av0.y, av0.z, av0.w, av1.x, av1.y, av1.z, av1.w};
      float b_[8] = {bv0.x, bv0.y, bv0.z, bv0.w, bv1.x, bv1.y, bv1.z, bv1.w};
      #pragma unroll
      for (int i = 0; i < 8; i++)
        #pragma unroll
        for (int j = 0; j < 8; j++) acc[i][j] = fmaf(a_[i], b_[j], acc[i][j]);
    }
    __syncthreads();
  }
  #pragma unroll
  for (int i = 0; i < 8; i++) {
    int r = row0 + ty * 8 + i;
    float* crow = C + (size_t)r * N;
    #pragma unroll
    for (int j = 0; j < 8; j++) {
      int c = col0 + tx * 8 + j;
      float vv = acc[i][j];
      if (bias) vv += bias[c];
      if (resid) vv += resid[(size_t)r * N + c];
      if (relu) vv = fmaxf(vv, 0.f);
      crow[c] = vv;
    }
  }
}

// ---------------- attention (causal MHA, online softmax) ----------------
__global__ __launch_bounds__(64) void attn_kernel(
    const float* __restrict__ q, const float* __restrict__ k,
    const float* __restrict__ v, float* __restrict__ out) {
  __shared__ float Qs[64][68];
  __shared__ float Ks[64][64];
  __shared__ float Vs[64][64];
  int l = threadIdx.x;
  int qc = blockIdx.x & 3;
  int h = (blockIdx.x >> 2) & 7;
  int b = blockIdx.x >> 5;
  size_t base = ((size_t)b * SEQ) * DD + h * HSZ;
  for (int rr = 0; rr < 64; rr++)
    Qs[rr][l] = q[base + (size_t)(qc * 64 + rr) * DD + l] * 0.125f;
  __syncthreads();
  float qreg[64];
  #pragma unroll
  for (int d4 = 0; d4 < 16; d4++) {
    float4 t = *(const float4*)&Qs[l][d4 * 4];
    qreg[d4 * 4 + 0] = t.x; qreg[d4 * 4 + 1] = t.y;
    qreg[d4 * 4 + 2] = t.z; qreg[d4 * 4 + 3] = t.w;
  }
  float acc[64];
  #pragma unroll
  for (int d = 0; d < 64; d++) acc[d] = 0.f;
  float m = -INFINITY, lsum = 0.f;
  int qrow = qc * 64 + l;
  #pragma unroll 1
  for (int kc = 0; kc <= qc; kc++) {
    __syncthreads();
    for (int rr = 0; rr < 64; rr++) {
      Ks[rr][l] = k[base + (size_t)(kc * 64 + rr) * DD + l];
      Vs[rr][l] = v[base + (size_t)(kc * 64 + rr) * DD + l];
    }
    __syncthreads();
    #pragma unroll 1
    for (int sub = 0; sub < 4; sub++) {
      int j0 = sub * 16;
      float s[16];
      #pragma unroll
      for (int jj = 0; jj < 16; jj++) {
        float a = 0.f;
        #pragma unroll
        for (int d4 = 0; d4 < 16; d4++) {
          float4 kv = *(const float4*)&Ks[j0 + jj][d4 * 4];
          a = fmaf(qreg[d4 * 4 + 0], kv.x, a);
          a = fmaf(qreg[d4 * 4 + 1], kv.y, a);
          a = fmaf(qreg[d4 * 4 + 2], kv.z, a);
          a = fmaf(qreg[d4 * 4 + 3], kv.w, a);
        }
        int kglob = kc * 64 + j0 + jj;
        s[jj] = (kglob <= qrow) ? a : -INFINITY;
      }
      float cm = m;
      #pragma unroll
      for (int jj = 0; jj < 16; jj++) cm = fmaxf(cm, s[jj]);
      if (cm == -INFINITY) continue;
      float scale = __expf(m - cm);
      lsum *= scale;
      #pragma unroll
      for (int jj = 0; jj < 16; jj++) { s[jj] = __expf(s[jj] - cm); lsum += s[jj]; }
      #pragma unroll
      for (int d = 0; d < 64; d++) acc[d] *= scale;
      #pragma unroll
      for (int jj = 0; jj < 16; jj++) {
        #pragma unroll
        for (int d4 = 0; d4 < 16; d4++) {
          float4 vv = *(const float4*)&Vs[j0 + jj][d4 * 4];
          acc[d4 * 4 + 0] = fmaf(s[jj], vv.x, acc[d4 * 4 + 0]);
          acc[d4 * 4 + 1] = fmaf(s[jj], vv.y, acc[d4 * 4 + 1]);
          acc[d4 * 4 + 2] = fmaf(s[jj], vv.z, acc[d4 * 4 + 2]);
          acc[d4 * 4 + 3] = fmaf(s[jj], vv.w, acc[d4 * 4 + 3]);
        }
      }
      m = cm;
    }
  }
  float inv = 1.f / lsum;
  float* orow = out + base + (size_t)qrow * DD;
  #pragma unroll
  for (int d = 0; d < 64; d++) orow[d] = acc[d] * inv;
}

// ---------------- MoE router (fp32 — expert picks must not flip) -----------
__global__ __launch_bounds__(64) void router_kernel(
    const float* __restrict__ Y, const float* __restrict__ RW,
    const float* __restrict__ RB, const float* __restrict__ NW,
    const float* __restrict__ NBv, const float* __restrict__ noise,
    int* __restrict__ idx, float* __restrict__ gate, int* __restrict__ counts) {
  int t = blockIdx.x;
  int l = threadIdx.x;
  float accr[8] = {}, accn[8] = {};
  for (int i = l; i < DO; i += 64) {
    float yv = Y[(size_t)t * DO + i];
    float4 r0 = *(const float4*)(RW + (size_t)i * 8);
    float4 r1 = *(const float4*)(RW + (size_t)i * 8 + 4);
    float4 n0 = *(const float4*)(NW + (size_t)i * 8);
    float4 n1 = *(const float4*)(NW + (size_t)i * 8 + 4);
    accr[0] = fmaf(yv, r0.x, accr[0]); accr[1] = fmaf(yv, r0.y, accr[1]);
    accr[2] = fmaf(yv, r0.z, accr[2]); accr[3] = fmaf(yv, r0.w, accr[3]);
    accr[4] = fmaf(yv, r1.x, accr[4]); accr[5] = fmaf(yv, r1.y, accr[5]);
    accr[6] = fmaf(yv, r1.z, accr[6]); accr[7] = fmaf(yv, r1.w, accr[7]);
    accn[0] = fmaf(yv, n0.x, accn[0]); accn[1] = fmaf(yv, n0.y, accn[1]);
    accn[2] = fmaf(yv, n0.z, accn[2]); accn[3] = fmaf(yv, n0.w, accn[3]);
    accn[4] = fmaf(yv, n1.x, accn[4]); accn[5] = fmaf(yv, n1.y, accn[5]);
    accn[6] = fmaf(yv, n1.z, accn[6]); accn[7] = fmaf(yv, n1.w, accn[7]);
  }
  #pragma unroll
  for (int e = 0; e < 8; e++) {
    #pragma unroll
    for (int off = 32; off; off >>= 1) {
      accr[e] += __shfl_xor(accr[e], off);
      accn[e] += __shfl_xor(accn[e], off);
    }
  }
  if (l == 0) {
    float noisy[8];
    #pragma unroll
    for (int e = 0; e < 8; e++) {
      float nl = accn[e] + NBv[e];
      float sp = nl > 0.f ? nl + log1pf(expf(-nl)) : log1pf(expf(nl));
      noisy[e] = accr[e] + RB[e] + noise[(size_t)t * 8 + e] * sp;
    }
    int i0 = 0;
    #pragma unroll
    for (int e = 1; e < 8; e++) if (noisy[e] > noisy[i0]) i0 = e;
    int i1 = -1;
    #pragma unroll
    for (int e = 0; e < 8; e++)
      if (e != i0 && (i1 < 0 || noisy[e] > noisy[i1])) i1 = e;
    float v0 = noisy[i0], v1 = noisy[i1];
    float e1 = expf(v1 - v0);
    float inv = 1.f / (1.f + e1);
    idx[2 * t] = i0; idx[2 * t + 1] = i1;
    gate[2 * t] = inv; gate[2 * t + 1] = e1 * inv;
    atomicAdd(&counts[i0], 1);
    atomicAdd(&counts[i1], 1);
  }
}

__global__ void init_kernel(int* assign_tok, int* counts) {
  int i = blockIdx.x * 256 + threadIdx.x;
  if (i < MAXROWS) assign_tok[i] = -1;
  if (i < NEXP) counts[i] = 0;
}

__global__ void prefix_kernel(const int* counts, int* offs, int* cursor) {
  if (threadIdx.x == 0 && blockIdx.x == 0) {
    int o = 0;
    offs[0] = 0;
    for (int e = 0; e < NEXP; e++) {
      cursor[e] = 0;
      o += ((counts[e] + BM - 1) / BM) * BM;
      offs[e + 1] = o;
    }
  }
}

__global__ __launch_bounds__(256) void build_kernel(
    const int* __restrict__ idx, const float* __restrict__ gate,
    const int* __restrict__ offs, int* cursor,
    int* assign_tok, float* assign_gate) {
  int t = blockIdx.x * 256 + threadIdx.x;
  if (t >= TTOK) return;
  for (int k = 0; k < 2; k++) {
    int e = idx[2 * t + k];
    int pos = atomicAdd(&cursor[e], 1);
    int r = offs[e] + pos;
    assign_tok[r] = t;
    assign_gate[r] = gate[2 * t + k];
  }
}

// ---------------- fp32 -> bf16 converters ----------------
__global__ __launch_bounds__(256) void conv_a(const float* __restrict__ in,
                                              short* __restrict__ out, int n) {
  int i = (blockIdx.x * 256 + threadIdx.x) * 8;
  if (i >= n) return;
  float4 f0 = *(const float4*)(in + i);
  float4 f1 = *(const float4*)(in + i + 4);
  short8v o;
  o[0] = f2bf(f0.x); o[1] = f2bf(f0.y); o[2] = f2bf(f0.z); o[3] = f2bf(f0.w);
  o[4] = f2bf(f1.x); o[5] = f2bf(f1.y); o[6] = f2bf(f1.z); o[7] = f2bf(f1.w);
  *(short8v*)(out + i) = o;
}

// transpose+convert expert weights: W[e][Kd][Nd] f32 -> Wt[e][Nd][Kd] bf16
__global__ __launch_bounds__(256) void conv_w(const float* __restrict__ W,
                                              short* __restrict__ Wt,
                                              int Kd, int Nd) {
  __shared__ float t[64][65];
  int e = blockIdx.z;
  int n0 = blockIdx.x * 64, k0 = blockIdx.y * 64;
  const float* Wb = W + (size_t)e * Kd * Nd;
  short* Wtb = Wt + (size_t)e * Kd * Nd;
  int c = threadIdx.x & 63, r4 = threadIdx.x >> 6;
  #pragma unroll
  for (int i = 0; i < 16; i++) {
    int r = r4 + i * 4;
    t[c][r] = Wb[(size_t)(k0 + r) * Nd + n0 + c];   // t[n_local][k_local]
  }
  __syncthreads();
  #pragma unroll
  for (int i = 0; i < 16; i++) {
    int rr = r4 + i * 4;
    Wtb[(size_t)(n0 + rr) * Kd + k0 + c] = f2bf(t[rr][c]);
  }
}

// ---------------- MFMA grouped expert GEMMs (bf16 in, fp32 acc) ------------
// MODE 0: H[row] = relu(bf16(Y[tok(row)]) @ W1bf[e] + b1[e]) -> Hbuf bf16
// MODE 1: Out[tok(row)] += gate(row) * (Hbuf[row] @ W2bf[e] + b2[e])
// Wt layout: [e][N][K] bf16 (K contiguous). Tile 128x128, BK=32, 4 waves.
template <int MODE>
__global__ __launch_bounds__(256) void moe_mfma(
    const short* __restrict__ Abase, const short* __restrict__ Wt,
    const float* __restrict__ bias, const int* __restrict__ offs,
    const int* __restrict__ assign_tok, const float* __restrict__ assign_gate,
    short* __restrict__ Hout, float* __restrict__ Out) {
  constexpr int Kd = MODE == 0 ? DO : FFD;
  constexpr int Nd = MODE == 0 ? FFD : DO;
  constexpr int NT = Kd / 32;
  __shared__ short As[2][128][40];   // +8 pad: fragment reads 2-way max (free)
  __shared__ short Bs[2][128][40];   // Bs[col][k]
  int row0 = blockIdx.y * BM;
  if (row0 >= offs[NEXP]) return;
  int e = 0;
  while (offs[e + 1] <= row0) e++;
  int n0 = blockIdx.x * 128;
  int tid = threadIdx.x;
  int l = tid & 63;
  int w = tid >> 6;
  int wr = (w >> 1) * 64, wc = (w & 1) * 64;   // wave's 64x64 quadrant
  int sr = tid >> 1;                           // staging row/col 0..127
  int sc = (tid & 1) * 8;                      // k-chunk 0 or 8 (plus +16)
  const short* Aptr;
  if (MODE == 0) {
    int tk = assign_tok[row0 + sr];
    Aptr = Abase + (size_t)(tk < 0 ? 0 : tk) * Kd;
  } else {
    Aptr = Abase + (size_t)(row0 + sr) * Kd;
  }
  const short* Bptr = Wt + ((size_t)e * Nd + (n0 + sr)) * (size_t)Kd;

  f32x4 acc[4][4];
  #pragma unroll
  for (int m = 0; m < 4; m++)
    #pragma unroll
    for (int n = 0; n < 4; n++) acc[m][n] = (f32x4){0.f, 0.f, 0.f, 0.f};

  short8v ra0, ra1, rb0, rb1;
  ra0 = *(const short8v*)(Aptr + sc);
  ra1 = *(const short8v*)(Aptr + sc + 16);
  rb0 = *(const short8v*)(Bptr + sc);
  rb1 = *(const short8v*)(Bptr + sc + 16);
  *(short8v*)&As[0][sr][sc]      = ra0;
  *(short8v*)&As[0][sr][sc + 16] = ra1;
  *(short8v*)&Bs[0][sr][sc]      = rb0;
  *(short8v*)&Bs[0][sr][sc + 16] = rb1;
  __syncthreads();

  int la = l & 15, lb = (l >> 4) * 8;   // fragment row/col, k-offset
  for (int t = 0; t < NT; t++) {
    if (t + 1 < NT) {                   // issue next-tile loads early (T14)
      int k0 = (t + 1) * 32;
      ra0 = *(const short8v*)(Aptr + k0 + sc);
      ra1 = *(const short8v*)(Aptr + k0 + sc + 16);
      rb0 = *(const short8v*)(Bptr + k0 + sc);
      rb1 = *(const short8v*)(Bptr + k0 + sc + 16);
    }
    int buf = t & 1;
    short8v af[4], bfr[4];
    #pragma unroll
    for (int m = 0; m < 4; m++)
      af[m] = *(const short8v*)&As[buf][wr + m * 16 + la][lb];
    #pragma unroll
    for (int n = 0; n < 4; n++)
      bfr[n] = *(const short8v*)&Bs[buf][wc + n * 16 + la][lb];
    #pragma unroll
    for (int m = 0; m < 4; m++)
      #pragma unroll
      for (int n = 0; n < 4; n++)
        acc[m][n] = __builtin_amdgcn_mfma_f32_16x16x32_bf16(af[m], bfr[n], acc[m][n], 0, 0, 0);
    if (t + 1 < NT) {                   // write-late into other buffer
      int nb = buf ^ 1;
      *(short8v*)&As[nb][sr][sc]      = ra0;
      *(short8v*)&As[nb][sr][sc + 16] = ra1;
      *(short8v*)&Bs[nb][sr][sc]      = rb0;
      *(short8v*)&Bs[nb][sr][sc + 16] = rb1;
    }
    __syncthreads();
  }

  // C/D layout (m89-verified): col = lane&15, row = (lane>>4)*4 + j
  int crb = (l >> 4) * 4;
  int ccol = l & 15;
  if (MODE == 0) {
    #pragma unroll
    for (int m = 0; m < 4; m++) {
      #pragma unroll
      for (int n = 0; n < 4; n++) {
        int c = n0 + wc + n * 16 + ccol;
        float bv = bias[e * Nd + c];
        #pragma unroll
        for (int j = 0; j < 4; j++) {
          int r = row0 + wr + m * 16 + crb + j;
          float v = acc[m][n][j] + bv;
          Hout[(size_t)r * Nd + c] = f2bf(fmaxf(v, 0.f));
        }
      }
    }
  } else {
    #pragma unroll
    for (int m = 0; m < 4; m++) {
      #pragma unroll
      for (int j = 0; j < 4; j++) {
        int r = row0 + wr + m * 16 + crb + j;
        int tk = assign_tok[r];
        if (tk < 0) continue;
        float g = assign_gate[r];
        #pragma unroll
        for (int n = 0; n < 4; n++) {
          int c = n0 + wc + n * 16 + ccol;
          atomicAdd(&Out[(size_t)tk * Nd + c], g * (acc[m][n][j] + bias[e * Nd + c]));
        }
      }
    }
  }
}

// ---------------- epilogue ----------------
__global__ __launch_bounds__(256) void mean_kernel(const float* __restrict__ second,
                                                   float* __restrict__ tv) {
  int o = blockIdx.x * 256 + threadIdx.x;
  int b = blockIdx.y;
  float s = 0.f;
  for (int ss = 0; ss < SEQ; ss++) s += second[((size_t)b * SEQ + ss) * DO + o];
  tv[(size_t)b * DO + o] = s * (1.f / SEQ);
}

__global__ __launch_bounds__(256) void cls_kernel(const float* __restrict__ tv,
                                                  const float* __restrict__ cw,
                                                  const float* __restrict__ cb,
                                                  float* __restrict__ outc) {
  __shared__ float red[4];
  int b = blockIdx.x;
  float s = 0.f;
  for (int o = threadIdx.x; o < DO; o += 256) s += tv[(size_t)b * DO + o] * cw[o];
  s = block_reduce_sum(s, red);
  if (threadIdx.x == 0) outc[b] = s + cb[0];
}

// ---------------- launch ----------------
extern "C" void kernel_launch(void* const* d_in, const int* in_sizes, int n_in,
                              void* d_out, int out_size, void* d_ws, size_t ws_size,
                              hipStream_t stream) {
  const int*   ids   = (const int*)d_in[0];
  const float* emb   = (const float*)d_in[2];
  const float* pe    = (const float*)d_in[3];
  const float* wq    = (const float*)d_in[4];
  const float* wk    = (const float*)d_in[5];
  const float* wv    = (const float*)d_in[6];
  const float* wo    = (const float*)d_in[7];
  const float* bo    = (const float*)d_in[8];
  const float* ln1g  = (const float*)d_in[9];
  const float* ln1b  = (const float*)d_in[10];
  const float* projw = (const float*)d_in[11];
  const float* projb = (const float*)d_in[12];
  const float* ln2g  = (const float*)d_in[13];
  const float* ln2b  = (const float*)d_in[14];
  const float* ln3g  = (const float*)d_in[15];
  const float* ln3b  = (const float*)d_in[16];
  const float* clsw  = (const float*)d_in[17];
  const float* clsb  = (const float*)d_in[18];
  const float* rwp[2]  = {(const float*)d_in[19], (const float*)d_in[28]};
  const float* rbp[2]  = {(const float*)d_in[20], (const float*)d_in[29]};
  const float* nwp[2]  = {(const float*)d_in[21], (const float*)d_in[30]};
  const float* nbp[2]  = {(const float*)d_in[22], (const float*)d_in[31]};
  const float* ew1[2]  = {(const float*)d_in[23], (const float*)d_in[32]};
  const float* eb1[2]  = {(const float*)d_in[24], (const float*)d_in[33]};
  const float* ew2[2]  = {(const float*)d_in[25], (const float*)d_in[34]};
  const float* eb2[2]  = {(const float*)d_in[26], (const float*)d_in[35]};
  const float* noz[2]  = {(const float*)d_in[27], (const float*)d_in[36]};

  char* w = (char*)d_ws;
  auto alloc = [&](size_t bytes) {
    char* p = w;
    w += (bytes + 255) & ~(size_t)255;
    return p;
  };
  // ---- persistent region (live across dense + MoE phases) ----
  float* x3    = (float*)alloc((size_t)TTOK * DO * 4);     // 16 MB
  float* y     = (float*)alloc((size_t)TTOK * DO * 4);     // 16 MB
  short* ybf   = (short*)alloc((size_t)TTOK * DO * 2);     // 8 MB
  short* hbf   = (short*)alloc((size_t)MAXROWS * FFD * 2); // 75.5 MB
  short* wt1   = (short*)alloc((size_t)NEXP * DO * FFD * 2);  // 67 MB (MoE phase only)
  short* wt2   = (short*)alloc((size_t)NEXP * FFD * DO * 2);  // 67 MB (MoE phase only)
  int*   idxb  = (int*)alloc((size_t)TTOK * 2 * 4);
  float* gateb = (float*)alloc((size_t)TTOK * 2 * 4);
  int* counts  = (int*)alloc(256);
  int* offs    = (int*)alloc(256);
  int* cursor  = (int*)alloc(256);
  int* assign_tok    = (int*)alloc((size_t)MAXROWS * 4);
  float* assign_gate = (float*)alloc((size_t)MAXROWS * 4);

  // ---- dense-phase temporaries: alias into wt1/wt2 (134 MB; dead before conv_w) ----
  char* dt = (char*)wt1;
  const size_t DBUF = (size_t)TTOK * DD * 4;  // 8 MB each
  float* x     = (float*)(dt + 0 * DBUF);
  float* xln   = (float*)(dt + 1 * DBUF);
  float* qb    = (float*)(dt + 2 * DBUF);
  float* kb    = (float*)(dt + 3 * DBUF);
  float* vb    = (float*)(dt + 4 * DBUF);
  float* attnb = (float*)(dt + 5 * DBUF);
  float* x2    = (float*)(dt + 6 * DBUF);

  float* out_first  = (float*)d_out;
  float* out_second = out_first + (size_t)TTOK * DO;
  float* tv         = out_second + (size_t)TTOK * DO;
  float* outc       = tv + (size_t)NBATCH * DO;

  zero_kernel<<<(out_size + 255) / 256, 256, 0, stream>>>((float*)d_out, out_size);
  embed_kernel<<<TTOK, 256, 0, stream>>>(ids, emb, pe, x);
  ln_kernel<DD><<<TTOK, 256, 0, stream>>>(x, ln1g, ln1b, xln);
  gemm_f32<<<dim3(DD / BN, TTOK / BM), 256, 0, stream>>>(xln, wq, qb, TTOK, DD, DD, nullptr, nullptr, 0);
  gemm_f32<<<dim3(DD / BN, TTOK / BM), 256, 0, stream>>>(xln, wk, kb, TTOK, DD, DD, nullptr, nullptr, 0);
  gemm_f32<<<dim3(DD / BN, TTOK / BM), 256, 0, stream>>>(xln, wv, vb, TTOK, DD, DD, nullptr, nullptr, 0);
  attn_kernel<<<NBATCH * NHEAD * (SEQ / 64), 64, 0, stream>>>(qb, kb, vb, attnb);
  gemm_f32<<<dim3(DD / BN, TTOK / BM), 256, 0, stream>>>(attnb, wo, x2, TTOK, DD, DD, bo, x, 0);
  gemm_f32<<<dim3(DO / BN, TTOK / BM), 256, 0, stream>>>(x2, projw, x3, TTOK, DO, DD, projb, nullptr, 0);

  for (int p = 0; p < 2; p++) {
    const float* lng = p ? ln3g : ln2g;
    const float* lnb = p ? ln3b : ln2b;
    float* outp = p ? out_second : out_first;
    ln_kernel<DO><<<TTOK, 256, 0, stream>>>(x3, lng, lnb, y);
    init_kernel<<<(MAXROWS + 255) / 256, 256, 0, stream>>>(assign_tok, counts);
    router_kernel<<<TTOK, 64, 0, stream>>>(y, rwp[p], rbp[p], nwp[p], nbp[p], noz[p],
                                           idxb, gateb, counts);
    prefix_kernel<<<1, 64, 0, stream>>>(counts, offs, cursor);
    build_kernel<<<(TTOK + 255) / 256, 256, 0, stream>>>(idxb, gateb, offs, cursor,
                                                         assign_tok, assign_gate);
    // bf16 conversions for the expert path (dense temporaries dead from here on)
    conv_a<<<(TTOK * DO / 8 + 255) / 256, 256, 0, stream>>>(y, ybf, TTOK * DO);
    conv_w<<<dim3(FFD / 64, DO / 64, NEXP), 256, 0, stream>>>(ew1[p], wt1, DO, FFD);
    conv_w<<<dim3(DO / 64, FFD / 64, NEXP), 256, 0, stream>>>(ew2[p], wt2, FFD, DO);
    moe_mfma<0><<<dim3(FFD / 128, MAXTILES), 256, 0, stream>>>(
        ybf, wt1, eb1[p], offs, assign_tok, nullptr, hbf, nullptr);
    moe_mfma<1><<<dim3(DO / 128, MAXTILES), 256, 0, stream>>>(
        hbf, wt2, eb2[p], offs, assign_tok, assign_gate, nullptr, outp);
  }
  mean_kernel<<<dim3(DO / 256, NBATCH), 256, 0, stream>>>(out_second, tv);
  cls_kernel<<<NBATCH, 256, 0, stream>>>(tv, clsw, clsb, outc);
}